// Round 3
// baseline (55.047 us; speedup 1.0000x reference)
//
#include <hip/hip_runtime.h>
#include <math.h>

#define NTHREADS 512
#define MAXN 4096
#define PER 8          // MAXN / NTHREADS
#define DETS 100

__device__ __forceinline__ unsigned long long shfl_xor64(unsigned long long x, int m) {
    int lo = __shfl_xor((int)(unsigned)x, m, 64);
    int hi = __shfl_xor((int)(unsigned)(x >> 32), m, 64);
    return ((unsigned long long)(unsigned)hi << 32) | (unsigned)lo;
}
__device__ __forceinline__ unsigned long long shfl_bc64(unsigned long long x, int src) {
    int lo = __shfl((int)(unsigned)x, src, 64);
    int hi = __shfl((int)(unsigned)(x >> 32), src, 64);
    return ((unsigned long long)(unsigned)hi << 32) | (unsigned)lo;
}

__device__ __forceinline__ float iou_f(float ax1, float ay1, float ax2, float ay2, float aar,
                                       float bx1, float by1, float bx2, float by2, float bar) {
#pragma clang fp contract(off)
    float xx1 = fmaxf(ax1, bx1), yy1 = fmaxf(ay1, by1);
    float xx2 = fminf(ax2, bx2), yy2 = fminf(ay2, by2);
    float iw = fmaxf((xx2 - xx1) + 1.0f, 0.0f);
    float ih = fmaxf((yy2 - yy1) + 1.0f, 0.0f);
    float inter = iw * ih;
    return inter / ((aar + bar) - inter);
}

__global__ __launch_bounds__(NTHREADS) void postproc_kernel(
    const float* __restrict__ logits,   // (B,N,2)
    const float* __restrict__ regr,     // (B,N,8)
    const float* __restrict__ props,    // (B,N,4)
    float* __restrict__ out,            // (B,100,5) ++ (B,100) ++ (B,100)
    int B, int N)
{
#pragma clang fp contract(off)
    const int b    = blockIdx.x;
    const int tid  = threadIdx.x;
    const int base = tid * PER;

    __shared__ unsigned long long keys[MAXN];   // 32 KB
    __shared__ float sc[MAXN];                  // 16 KB
    __shared__ float tb[6][64];                 // tile boxes: x1,y1,x2,y2,area,score
    __shared__ float kb[5][DETS + 64];          // kept boxes
    __shared__ unsigned tmask[64][2];           // intra-tile suppression rows
    __shared__ unsigned supk[64];               // suppressed-by-kept / invalid
    __shared__ int keptCount;

    const float* lg = logits + (size_t)b * N * 2;
    const float* rg = regr   + (size_t)b * N * 8;
    const float* pp = props  + (size_t)b * N * 4;

    // ---------------- Phase A: scores + sort keys (registers) ----------------
    unsigned long long v[PER];
#pragma unroll
    for (int s = 0; s < PER; ++s) {
        int a = base + s;
        unsigned long long key;
        float score = 0.0f;
        if (a < N) {
            float2 l = ((const float2*)lg)[a];
            float m  = fmaxf(l.x, l.y);
            float e0 = (float)exp((double)(l.x - m));
            float e1 = (float)exp((double)(l.y - m));
            score = e1 / (e0 + e1);
            float f = (score > 0.05f) ? score : -1e30f;
            unsigned u = __float_as_uint(f);
            u = (u & 0x80000000u) ? ~u : (u | 0x80000000u);   // monotone float->uint
            key = ((unsigned long long)(~u) << 32) | (unsigned)a;  // asc => score desc, idx asc
        } else {
            key = 0xFFFFFFFFFFFFFFFFull;
        }
        v[s] = key;
        sc[a] = score;
    }

    // compare-exchange on static register indices
    auto cexch = [&](int si, int ti, bool up) {
        unsigned long long a = v[si], c2 = v[ti];
        bool sw = (a > c2) == up;
        v[si] = sw ? c2 : a;
        v[ti] = sw ? a : c2;
    };

    // ---------------- Phase B: hybrid bitonic sort ----------------
    for (unsigned k = 2; k <= (unsigned)MAXN; k <<= 1) {
        for (unsigned j = k >> 1; j > 0; j >>= 1) {
            if (j >= 512) {
                // cross-wave: stage through LDS
                __syncthreads();
#pragma unroll
                for (int s = 0; s < PER; ++s) keys[base + s] = v[s];
                __syncthreads();
                bool up = ((base & (int)k) == 0);
                bool keepmin = (((base & (int)j) == 0) == up);
                int pb = base ^ (int)j;
#pragma unroll
                for (int s = 0; s < PER; ++s) {
                    unsigned long long p = keys[pb + s];
                    unsigned long long mn = v[s] < p ? v[s] : p;
                    unsigned long long mx = v[s] < p ? p : v[s];
                    v[s] = keepmin ? mn : mx;
                }
            } else if (j >= 8) {
                // intra-wave shfl exchange
                bool up = ((base & (int)k) == 0);
                bool keepmin = (((base & (int)j) == 0) == up);
                int m = (int)(j >> 3);
#pragma unroll
                for (int s = 0; s < PER; ++s) {
                    unsigned long long p = shfl_xor64(v[s], m);
                    unsigned long long mn = v[s] < p ? v[s] : p;
                    unsigned long long mx = v[s] < p ? p : v[s];
                    v[s] = keepmin ? mn : mx;
                }
            } else if (j == 4) {
                cexch(0, 4, ((base + 0) & (int)k) == 0);
                cexch(1, 5, ((base + 1) & (int)k) == 0);
                cexch(2, 6, ((base + 2) & (int)k) == 0);
                cexch(3, 7, ((base + 3) & (int)k) == 0);
            } else if (j == 2) {
                cexch(0, 2, ((base + 0) & (int)k) == 0);
                cexch(1, 3, ((base + 1) & (int)k) == 0);
                cexch(4, 6, ((base + 4) & (int)k) == 0);
                cexch(5, 7, ((base + 5) & (int)k) == 0);
            } else { // j == 1
                cexch(0, 1, ((base + 0) & (int)k) == 0);
                cexch(2, 3, ((base + 2) & (int)k) == 0);
                cexch(4, 5, ((base + 4) & (int)k) == 0);
                cexch(6, 7, ((base + 6) & (int)k) == 0);
            }
        }
    }
    __syncthreads();
#pragma unroll
    for (int s = 0; s < PER; ++s) keys[base + s] = v[s];
    __syncthreads();

    // ---------------- Phase C: tiled greedy NMS ----------------
    float* obox = out + (size_t)b * DETS * 5;
    float* olab = out + (size_t)B * DETS * 5 + (size_t)b * DETS;
    float* oval = out + (size_t)B * DETS * 5 + (size_t)B * DETS + (size_t)b * DETS;
    const float CLIPV = (float)4.135166556742356;   // log(1000/16)

    int kept = 0;
    for (int i0 = 0; i0 < N && kept < DETS; i0 += 64) {
        // decode this tile's candidates
        if (tid < 64) {
            int r = i0 + tid;
            bool valid = false;
            if (r < N) {
                unsigned long long key = keys[r];
                unsigned idx = (unsigned)(key & 0xFFFFFFFFull);
                if (idx < (unsigned)N) {
                    float score = sc[idx];
                    if (score > 0.05f) {
                        valid = true;
                        float4 p  = ((const float4*)pp)[idx];
                        float4 rr = *(const float4*)(rg + (size_t)idx * 8 + 4);
                        float w  = (p.z - p.x) + 1.0f;
                        float h  = (p.w - p.y) + 1.0f;
                        float cx = p.x + 0.5f * w;
                        float cy = p.y + 0.5f * h;
                        float dx = rr.x / 10.0f;
                        float dy = rr.y / 10.0f;
                        float dw = fminf(rr.z / 5.0f, CLIPV);
                        float dh = fminf(rr.w / 5.0f, CLIPV);
                        float pcx = dx * w + cx;
                        float pcy = dy * h + cy;
                        float ew = (float)exp((double)dw);
                        float eh = (float)exp((double)dh);
                        float pw = ew * w;
                        float ph = eh * h;
                        float x1 = pcx - 0.5f * pw;
                        float y1 = pcy - 0.5f * ph;
                        float x2 = (pcx + 0.5f * pw) - 1.0f;
                        float y2 = (pcy + 0.5f * ph) - 1.0f;
                        x1 = fminf(fmaxf(x1, 0.0f), 511.0f);
                        y1 = fminf(fmaxf(y1, 0.0f), 511.0f);
                        x2 = fminf(fmaxf(x2, 0.0f), 511.0f);
                        y2 = fminf(fmaxf(y2, 0.0f), 511.0f);
                        tb[0][tid] = x1; tb[1][tid] = y1;
                        tb[2][tid] = x2; tb[3][tid] = y2;
                        tb[4][tid] = ((x2 - x1) + 1.0f) * ((y2 - y1) + 1.0f);
                        tb[5][tid] = score;
                    }
                }
            }
            supk[tid] = valid ? 0u : 1u;
        } else if (tid < 192) {
            int q = tid - 64;
            tmask[q >> 1][q & 1] = 0u;
        }
        __syncthreads();

        // candidate-vs-kept suppression (64 candidates x 8 slices)
        {
            int c = tid & 63, sl = tid >> 6;
            if (supk[c] == 0u) {
                float x1 = tb[0][c], y1 = tb[1][c], x2 = tb[2][c], y2 = tb[3][c], ar = tb[4][c];
                for (int s = sl; s < kept; s += 8) {
                    float iou = iou_f(kb[0][s], kb[1][s], kb[2][s], kb[3][s], kb[4][s],
                                      x1, y1, x2, y2, ar);
                    if (iou > 0.5f) { supk[c] = 1u; break; }
                }
            }
        }
        // intra-tile 64x64 suppression rows (i suppresses j>i if IoU>0.5)
        {
            int i = tid >> 3, jb = (tid & 7) << 3;
            float x1 = tb[0][i], y1 = tb[1][i], x2 = tb[2][i], y2 = tb[3][i], ar = tb[4][i];
            unsigned byte = 0;
#pragma unroll
            for (int u = 0; u < 8; ++u) {
                int j = jb + u;
                if (j > i) {
                    float iou = iou_f(x1, y1, x2, y2, ar,
                                      tb[0][j], tb[1][j], tb[2][j], tb[3][j], tb[4][j]);
                    if (iou > 0.5f) byte |= (1u << u);
                }
            }
            if (byte) atomicOr(&tmask[i][jb >> 5], byte << (jb & 31));
        }
        __syncthreads();

        // wave 0: greedy resolve, iterating ONLY over live suppressors
        if (tid < 64) {
            int l = tid;
            unsigned long long row = ((unsigned long long)tmask[l][1] << 32) | tmask[l][0];
            int alive0 = supk[l] ? 0 : 1;
            unsigned long long aliveMask = __ballot(alive0);
            unsigned long long pend = __ballot(alive0 && row != 0ull);
            while (pend) {
                int c = __ffsll((unsigned long long)pend) - 1;
                unsigned long long rc = shfl_bc64(row, c);
                aliveMask &= ~rc;           // rc only has bits > c
                pend &= ~(1ull << c);
                pend &= aliveMask;
            }
            int alive = (int)((aliveMask >> l) & 1ull);
            int rank = kept + (int)__popcll(aliveMask & ((1ull << l) - 1ull));
            if (alive) {
                if (rank < DETS) {
                    float* o = obox + rank * 5;
                    o[0] = tb[0][l]; o[1] = tb[1][l]; o[2] = tb[2][l]; o[3] = tb[3][l];
                    o[4] = tb[5][l];
                    olab[rank] = 1.0f;
                    oval[rank] = 1.0f;
                }
                kb[0][rank] = tb[0][l]; kb[1][rank] = tb[1][l];
                kb[2][rank] = tb[2][l]; kb[3][rank] = tb[3][l];
                kb[4][rank] = tb[4][l];
            }
            if (l == 0) keptCount = kept + (int)__popcll(aliveMask);
        }
        __syncthreads();
        kept = keptCount;
    }

    // ---------------- zero-fill remaining output rows ----------------
    int start = kept < DETS ? kept : DETS;
    for (int c = start + tid; c < DETS; c += NTHREADS) {
        float* o = obox + c * 5;
        o[0] = 0.0f; o[1] = 0.0f; o[2] = 0.0f; o[3] = 0.0f; o[4] = 0.0f;
        olab[c] = 0.0f;
        oval[c] = 0.0f;
    }
}

extern "C" void kernel_launch(void* const* d_in, const int* in_sizes, int n_in,
                              void* d_out, int out_size, void* d_ws, size_t ws_size,
                              hipStream_t stream) {
    (void)d_ws; (void)ws_size; (void)n_in;
    const float* logits = (const float*)d_in[0];
    const float* regr   = (const float*)d_in[1];
    const float* props  = (const float*)d_in[2];
    float* out = (float*)d_out;

    int B = out_size / 700;          // (100*5 + 100 + 100) per image
    if (B < 1) B = 1;
    int N = in_sizes[0] / (2 * B);   // logits = B*N*2

    postproc_kernel<<<B, NTHREADS, 0, stream>>>(logits, regr, props, out, B, N);
}

// Round 4
// 27.982 us; speedup vs baseline: 1.9672x; 1.9672x over previous
//
#include <hip/hip_runtime.h>
#include <math.h>

#define NTHREADS 512
#define MAXN 4096
#define PER 8            // keys per thread = MAXN / NTHREADS
#define DETS 100
#define CHUNK 256        // selection chunk (sorted per refill round)

static __device__ __forceinline__ unsigned long long shfl_xor64(unsigned long long x, int m) {
    int lo = __shfl_xor((int)(unsigned)x, m, 64);
    int hi = __shfl_xor((int)(unsigned)(x >> 32), m, 64);
    return ((unsigned long long)(unsigned)hi << 32) | (unsigned)lo;
}
static __device__ __forceinline__ unsigned long long shfl_bc64(unsigned long long x, int src) {
    int lo = __shfl((int)(unsigned)x, src, 64);
    int hi = __shfl((int)(unsigned)(x >> 32), src, 64);
    return ((unsigned long long)(unsigned)hi << 32) | (unsigned)lo;
}

static __device__ __forceinline__ float iou_f(float ax1, float ay1, float ax2, float ay2, float aar,
                                              float bx1, float by1, float bx2, float by2, float bar) {
#pragma clang fp contract(off)
    float xx1 = fmaxf(ax1, bx1), yy1 = fmaxf(ay1, by1);
    float xx2 = fminf(ax2, bx2), yy2 = fminf(ay2, by2);
    float iw = fmaxf((xx2 - xx1) + 1.0f, 0.0f);
    float ih = fmaxf((yy2 - yy1) + 1.0f, 0.0f);
    float inter = iw * ih;
    return inter / ((aar + bar) - inter);
}

__global__ __launch_bounds__(NTHREADS) void postproc_kernel(
    const float* __restrict__ logits,   // (B,N,2)
    const float* __restrict__ regr,     // (B,N,8)
    const float* __restrict__ props,    // (B,N,4)
    float* __restrict__ out,            // (B,100,5) ++ (B,100) ++ (B,100)
    int B, int N)
{
#pragma clang fp contract(off)
    const int b   = blockIdx.x;
    const int tid = threadIdx.x;

    __shared__ unsigned long long keysel[CHUNK];
    __shared__ unsigned hist[256];
    __shared__ float bx1s[CHUNK], by1s[CHUNK], bx2s[CHUNK], by2s[CHUNK], bars[CHUNK], bscs[CHUNK];
    __shared__ float kb[5][DETS + 64];          // kept boxes (global ranks)
    __shared__ unsigned tmask[64][2];
    __shared__ unsigned supk[64];
    __shared__ int s_kept;
    __shared__ int s_vcount;
    __shared__ int s_cnt;
    __shared__ unsigned long long s_prefix, s_T;
    __shared__ int s_target, s_done, s_findkey;

    const float* lg = logits + (size_t)b * N * 2;
    const float* rg = regr   + (size_t)b * N * 8;
    const float* pp = props  + (size_t)b * N * 4;

    // ---------------- Phase A: keys in registers (coalesced loads) ----------------
    unsigned long long v[PER];
    int nval = 0;
#pragma unroll
    for (int s = 0; s < PER; ++s) {
        int a = s * NTHREADS + tid;
        unsigned long long key;
        if (a < N) {
            float2 l = ((const float2*)lg)[a];
            // softmax[:,1] bit-exact to ref: one arg of exp is exactly 0 -> e=1
            float zmax = fmaxf(l.x, l.y), zmin = fminf(l.x, l.y);
            float e   = (float)exp((double)(zmin - zmax));
            float den = e + 1.0f;
            float sscore = (l.y >= l.x) ? (1.0f / den) : (e / den);
            bool valid = sscore > 0.05f;
            nval += valid ? 1 : 0;
            float f = valid ? sscore : -1e30f;
            unsigned u = __float_as_uint(f);
            u = (u & 0x80000000u) ? ~u : (u | 0x80000000u);     // monotone float->uint
            key = ((unsigned long long)(~u) << 32) | (unsigned)a; // small key = best
        } else key = ~0ull;
        v[s] = key;
    }

    if (tid == 0) { s_vcount = 0; s_kept = 0; }
    __syncthreads();
    {   // block-wide valid count (one atomic per wave)
        int c = nval;
#pragma unroll
        for (int off = 32; off; off >>= 1) c += __shfl_xor(c, off, 64);
        if ((tid & 63) == 0) atomicAdd(&s_vcount, c);
    }
    __syncthreads();
    const int V = s_vcount;

    float* obox = out + (size_t)b * DETS * 5;
    float* olab = out + (size_t)B * DETS * 5 + (size_t)b * DETS;
    float* oval = out + (size_t)B * DETS * 5 + (size_t)B * DETS + (size_t)b * DETS;
    const float CLIPV = (float)4.135166556742356;   // log(1000/16)

    int kept = 0, Mdone = 0;
    unsigned long long Tprev = 0ull;   // all real keys are > 0 (key32 >= 0x407FFFFF)

    while (kept < DETS && Mdone < V) {
        int targetGlobal = Mdone + CHUNK; if (targetGlobal > V) targetGlobal = V;

        // -------- radix-select: T = targetGlobal-th smallest key --------
        if (tid == 0) { s_prefix = 0ull; s_target = targetGlobal; s_done = 0; s_findkey = 0; s_cnt = 0; }
        for (int round = 0; round < 10; ++round) {
            __syncthreads();
            if (s_done) break;                       // uniform
            int sh = 56 - 8 * round;
            if (s_findkey) {                         // unique key with prefix: find it
                unsigned long long want = s_prefix; int shh = sh + 8;
#pragma unroll
                for (int s = 0; s < PER; ++s)
                    if ((v[s] >> shh) == want) { s_T = v[s]; s_done = 1; }
                continue;
            }
            if (tid < 256) hist[tid] = 0u;
            __syncthreads();
            unsigned long long pfx = s_prefix;
#pragma unroll
            for (int s = 0; s < PER; ++s) {
                unsigned long long k = v[s];
                bool match = (round == 0) || ((k >> (sh + 8)) == pfx);
                if (match) atomicAdd(&hist[(unsigned)((k >> sh) & 0xFFull)], 1u);
            }
            __syncthreads();
            if (tid < 64) {
                int l = tid;
                unsigned c0 = hist[4*l+0], c1 = hist[4*l+1], c2 = hist[4*l+2], c3 = hist[4*l+3];
                unsigned q0 = c0, q1 = q0 + c1, q2 = q1 + c2, q3 = q2 + c3;
                int lanesum = (int)q3, incl = lanesum;
#pragma unroll
                for (int off = 1; off < 64; off <<= 1) {
                    int y = __shfl_up(incl, off, 64);
                    if (l >= off) incl += y;
                }
                unsigned excl = (unsigned)(incl - lanesum);
                unsigned tgt = (unsigned)s_target;
                bool has = (excl < tgt) && (tgt <= (unsigned)incl);
                if (has) {
                    unsigned within = tgt - excl;
                    int u_; unsigned below, bc;
                    if      (within <= q0) { u_ = 0; below = excl;      bc = c0; }
                    else if (within <= q1) { u_ = 1; below = excl + q0; bc = c1; }
                    else if (within <= q2) { u_ = 2; below = excl + q1; bc = c2; }
                    else                   { u_ = 3; below = excl + q2; bc = c3; }
                    unsigned long long npfx = (pfx << 8) | (unsigned)(4*l + u_);
                    s_target = (int)(tgt - below);
                    if (sh == 0) { s_T = npfx; s_done = 1; }
                    else { s_prefix = npfx; if (bc == 1u) s_findkey = 1; }
                }
            }
        }
        __syncthreads();
        unsigned long long T = s_T;

        // -------- compact keys in (Tprev, T] (order fixed by the sort below) --------
#pragma unroll
        for (int s = 0; s < PER; ++s) {
            unsigned long long k = v[s];
            if (k > Tprev && k <= T) { int p = atomicAdd(&s_cnt, 1); keysel[p] = k; }
        }
        __syncthreads();
        int cnt = s_cnt;                              // == targetGlobal - Mdone
        for (int i = cnt + tid; i < CHUNK; i += NTHREADS) keysel[i] = ~0ull;
        __syncthreads();

        // -------- wave0: in-register bitonic sort of 256 keys (4/lane) --------
        if (tid < 64) {
            int b4 = tid * 4;
            unsigned long long w[4];
            w[0] = keysel[b4]; w[1] = keysel[b4+1]; w[2] = keysel[b4+2]; w[3] = keysel[b4+3];
            for (unsigned k2 = 2; k2 <= (unsigned)CHUNK; k2 <<= 1) {
                for (unsigned j = k2 >> 1; j; j >>= 1) {
                    if (j >= 4) {
                        bool up = ((b4 & (int)k2) == 0);
                        bool keepmin = (((b4 & (int)j) == 0) == up);
                        int m = (int)(j >> 2);
#pragma unroll
                        for (int s = 0; s < 4; ++s) {
                            unsigned long long p = shfl_xor64(w[s], m);
                            unsigned long long mn = w[s] < p ? w[s] : p;
                            unsigned long long mx = w[s] < p ? p : w[s];
                            w[s] = keepmin ? mn : mx;
                        }
                    } else if (j == 2) {
                        bool up = ((b4 & (int)k2) == 0);
                        { unsigned long long a0=w[0], c2v=w[2];
                          bool sw=(a0>c2v)==up; w[0]=sw?c2v:a0; w[2]=sw?a0:c2v; }
                        { unsigned long long a0=w[1], c2v=w[3];
                          bool sw=(a0>c2v)==up; w[1]=sw?c2v:a0; w[3]=sw?a0:c2v; }
                    } else {  // j == 1
                        bool up0 = (((b4 + 0) & (int)k2) == 0);
                        bool up1 = (((b4 + 2) & (int)k2) == 0);
                        { unsigned long long a0=w[0], c2v=w[1];
                          bool sw=(a0>c2v)==up0; w[0]=sw?c2v:a0; w[1]=sw?a0:c2v; }
                        { unsigned long long a0=w[2], c2v=w[3];
                          bool sw=(a0>c2v)==up1; w[2]=sw?c2v:a0; w[3]=sw?a0:c2v; }
                    }
                }
            }
            keysel[b4] = w[0]; keysel[b4+1] = w[1]; keysel[b4+2] = w[2]; keysel[b4+3] = w[3];
        }
        __syncthreads();

        // -------- decode all selected candidates once --------
        if (tid < CHUNK) {
            float x1 = 0, y1 = 0, x2 = 0, y2 = 0, ar = 0, sv = 0;
            if (tid < cnt) {
                unsigned long long key = keysel[tid];
                unsigned idx = (unsigned)(key & 0xFFFFFFFFull);
                float2 l = ((const float2*)lg)[idx];
                float zmax = fmaxf(l.x, l.y), zmin = fminf(l.x, l.y);
                float e = (float)exp((double)(zmin - zmax));
                float den = e + 1.0f;
                sv = (l.y >= l.x) ? (1.0f / den) : (e / den);
                float4 p  = ((const float4*)pp)[idx];
                float4 rr = *(const float4*)(rg + (size_t)idx * 8 + 4);
                float w  = (p.z - p.x) + 1.0f;
                float h  = (p.w - p.y) + 1.0f;
                float cx = p.x + 0.5f * w;
                float cy = p.y + 0.5f * h;
                float dx = rr.x / 10.0f;
                float dy = rr.y / 10.0f;
                float dw = fminf(rr.z / 5.0f, CLIPV);
                float dh = fminf(rr.w / 5.0f, CLIPV);
                float pcx = dx * w + cx;
                float pcy = dy * h + cy;
                float ew = (float)exp((double)dw);
                float eh = (float)exp((double)dh);
                float pw = ew * w;
                float ph = eh * h;
                x1 = pcx - 0.5f * pw;
                y1 = pcy - 0.5f * ph;
                x2 = (pcx + 0.5f * pw) - 1.0f;
                y2 = (pcy + 0.5f * ph) - 1.0f;
                x1 = fminf(fmaxf(x1, 0.0f), 511.0f);
                y1 = fminf(fmaxf(y1, 0.0f), 511.0f);
                x2 = fminf(fmaxf(x2, 0.0f), 511.0f);
                y2 = fminf(fmaxf(y2, 0.0f), 511.0f);
                ar = ((x2 - x1) + 1.0f) * ((y2 - y1) + 1.0f);
            }
            bx1s[tid] = x1; by1s[tid] = y1; bx2s[tid] = x2; by2s[tid] = y2;
            bars[tid] = ar; bscs[tid] = sv;
        }
        __syncthreads();

        // -------- tiled greedy NMS over this chunk --------
        for (int i0 = 0; i0 < cnt && kept < DETS; i0 += 64) {
            if (tid < 64) supk[tid] = (i0 + tid < cnt) ? 0u : 1u;
            else if (tid < 192) { int q = tid - 64; tmask[q >> 1][q & 1] = 0u; }
            __syncthreads();

            // candidate vs already-kept (8 slices)
            {
                int cc = tid & 63, sl = tid >> 6;
                if (supk[cc] == 0u) {
                    int gi = i0 + cc;
                    float x1 = bx1s[gi], y1 = by1s[gi], x2 = bx2s[gi], y2 = by2s[gi], ar = bars[gi];
                    for (int s2 = sl; s2 < kept; s2 += 8) {
                        float iou = iou_f(kb[0][s2], kb[1][s2], kb[2][s2], kb[3][s2], kb[4][s2],
                                          x1, y1, x2, y2, ar);
                        if (iou > 0.5f) { supk[cc] = 1u; break; }
                    }
                }
            }
            // intra-tile 64x64 suppression rows
            {
                int i = tid >> 3, jb = (tid & 7) << 3;
                int gi = i0 + i;
                float x1 = bx1s[gi], y1 = by1s[gi], x2 = bx2s[gi], y2 = by2s[gi], ar = bars[gi];
                unsigned byte = 0;
#pragma unroll
                for (int u = 0; u < 8; ++u) {
                    int j = jb + u;
                    if (j > i) {
                        int gj = i0 + j;
                        float iou = iou_f(x1, y1, x2, y2, ar,
                                          bx1s[gj], by1s[gj], bx2s[gj], by2s[gj], bars[gj]);
                        if (iou > 0.5f) byte |= (1u << u);
                    }
                }
                if (byte) atomicOr(&tmask[i][jb >> 5], byte << (jb & 31));
            }
            __syncthreads();

            // wave0: greedy resolve (skip non-suppressors)
            if (tid < 64) {
                int l = tid;
                unsigned long long row = ((unsigned long long)tmask[l][1] << 32) | tmask[l][0];
                int alive0 = supk[l] ? 0 : 1;
                unsigned long long aliveMask = __ballot(alive0);
                unsigned long long pend = __ballot(alive0 && row != 0ull);
                while (pend) {
                    int c = __ffsll(pend) - 1;
                    unsigned long long rc = shfl_bc64(row, c);
                    aliveMask &= ~rc;                // rc only has bits > c
                    pend &= ~(1ull << c);
                    pend &= aliveMask;
                }
                int alive = (int)((aliveMask >> l) & 1ull);
                int rank = kept + (int)__popcll(aliveMask & ((1ull << l) - 1ull));
                int gi = i0 + l;
                if (alive) {
                    if (rank < DETS) {
                        float* o = obox + rank * 5;
                        o[0] = bx1s[gi]; o[1] = by1s[gi]; o[2] = bx2s[gi]; o[3] = by2s[gi];
                        o[4] = bscs[gi];
                        olab[rank] = 1.0f;
                        oval[rank] = 1.0f;
                    }
                    kb[0][rank] = bx1s[gi]; kb[1][rank] = by1s[gi];
                    kb[2][rank] = bx2s[gi]; kb[3][rank] = by2s[gi];
                    kb[4][rank] = bars[gi];
                }
                if (l == 0) s_kept = kept + (int)__popcll(aliveMask);
            }
            __syncthreads();
            kept = s_kept;
        }

        Mdone = targetGlobal;
        Tprev = T;
    }

    // ---------------- zero-fill remaining output rows ----------------
    int start = kept < DETS ? kept : DETS;
    for (int c2 = start + tid; c2 < DETS; c2 += NTHREADS) {
        float* o = obox + c2 * 5;
        o[0] = 0.0f; o[1] = 0.0f; o[2] = 0.0f; o[3] = 0.0f; o[4] = 0.0f;
        olab[c2] = 0.0f;
        oval[c2] = 0.0f;
    }
}

extern "C" void kernel_launch(void* const* d_in, const int* in_sizes, int n_in,
                              void* d_out, int out_size, void* d_ws, size_t ws_size,
                              hipStream_t stream) {
    (void)d_ws; (void)ws_size; (void)n_in;
    const float* logits = (const float*)d_in[0];
    const float* regr   = (const float*)d_in[1];
    const float* props  = (const float*)d_in[2];
    float* out = (float*)d_out;

    int B = out_size / 700;          // (100*5 + 100 + 100) per image
    if (B < 1) B = 1;
    int N = in_sizes[0] / (2 * B);   // logits = B*N*2

    postproc_kernel<<<B, NTHREADS, 0, stream>>>(logits, regr, props, out, B, N);
}